// Round 7
// baseline (757.699 us; speedup 1.0000x reference)
//
#include <hip/hip_runtime.h>
#include <cfloat>
#include <climits>
#include <math.h>

#define BN 16
#define QN 4096
#define GN 256
#define CN 80
#define NCOL 4
#define NPART 4

typedef unsigned long long u64;

__device__ __forceinline__ bool lexLessF(float a, int ia, float b, int ib) {
    return (a < b) || (a == b && ia < ib);
}

// ---------------- zero init (rowmask + colcnt + staleCount) ----------------
__global__ void k_zero(u64* __restrict__ p, int n) {
    int i = blockIdx.x * blockDim.x + threadIdx.x;
    if (i < n) p[i] = 0ull;
}

// ---------------- focal class-cost table: ccls[b][c][i] ----------------
__global__ __launch_bounds__(256) void k_class(const float* __restrict__ logits,
                                               float* __restrict__ ccls) {
#pragma clang fp contract(off)
    const int b = blockIdx.x >> 6, iblk = blockIdx.x & 63;
    const int lane = threadIdx.x & 63, cg = threadIdx.x >> 6;  // 4 c-groups x 20
    const int i = iblk * 64 + lane;
    const float* lrow = logits + ((size_t)(b * QN + i)) * CN;
    for (int c = cg * 20; c < cg * 20 + 20; c++) {
        float x = lrow[c];
        float e = (float)exp(-(double)x);
        float pr = 1.0f / (1.0f + e);
        float om = 1.0f - pr;
        float lneg = (float)log((double)(om + 1e-8f));
        float lpos = (float)log((double)(pr + 1e-8f));
        float neg = (0.75f * (pr * pr)) * (-lneg);
        float pos = (0.25f * (om * om)) * (-lpos);
        ccls[((size_t)b * CN + c) * QN + i] = pos - neg;
    }
}

// ---------------- fg per query row (f32, exact reference order) ----------------
__global__ __launch_bounds__(256) void k_fg(const float* __restrict__ gtb,
                                            const float* __restrict__ pb,
                                            unsigned char* __restrict__ fg) {
#pragma clang fp contract(off)
    int b = blockIdx.y;
    int i = blockIdx.x * 256 + threadIdx.x;
    __shared__ float s[GN][8];
    for (int j = threadIdx.x; j < GN; j += 256) {
        const float* g = gtb + ((size_t)(b * GN + j)) * 4;
        float g0 = g[0], g1 = g[1], g2 = g[2], g3 = g[3];
        float gcx = (g0 + g2) * 0.5f, gcy = (g1 + g3) * 0.5f;
        float gw = g2 - g0, gh = g3 - g1;
        float x0 = gcx - gw * 0.5f, y0 = gcy - gh * 0.5f;
        float x1 = gcx + gw * 0.5f, y1 = gcy + gh * 0.5f;
        float w = x1 - x0, h = y1 - y0;
        s[j][0] = x0; s[j][1] = y0; s[j][2] = x1; s[j][3] = y1;
        s[j][4] = gcx - 2.5f * w; s[j][5] = gcx + 2.5f * w;
        s[j][6] = gcy - 2.5f * h; s[j][7] = gcy + 2.5f * h;
    }
    __syncthreads();
    const float4 bb = *reinterpret_cast<const float4*>(pb + ((size_t)(b * QN + i)) * 4);
    float ax = (bb.x + bb.z) * 0.5f, ay = (bb.y + bb.w) * 0.5f;
    bool anyib = false, anyic = false;
    for (int j = 0; j < GN; j++) {
        bool ib = (ax > s[j][0]) && (ax < s[j][2]) && (ay > s[j][1]) && (ay < s[j][3]);
        bool ic = (ax > s[j][4]) && (ax < s[j][5]) && (ay > s[j][6]) && (ay < s[j][7]);
        anyib |= ib; anyic |= ic;
    }
    fg[(size_t)b * QN + i] = (anyib || anyic) ? 1 : 0;
}

// ---------------- cost matrix (f32) + per-column/per-part bottom-5 & top-5 ----------------
// NCOL columns per block (TA sharing) x NPART i-splits (occupancy). Static-index
// cascades only (no scratch). Partials written to ws; k_dk merges.
__global__ __launch_bounds__(256) void k_cost(
    const float* __restrict__ ccls, const float* __restrict__ pboxes,
    const float* __restrict__ pposes, const int* __restrict__ labels,
    const float* __restrict__ gtb, const float* __restrict__ gtt,
    const float* __restrict__ gtr, const float* __restrict__ img,
    const float* __restrict__ imgt, const unsigned char* __restrict__ fg,
    float* __restrict__ cost,
    float* __restrict__ pcv, int* __restrict__ pci, float* __restrict__ piv) {
#pragma clang fp contract(off)
    const int t = threadIdx.x;
    const int b = blockIdx.x >> 8;
    const int rem = blockIdx.x & 255;
    const int jblk = rem >> 2, part = rem & 3;
    const int j0 = jblk * NCOL;
    const int ibase = part * (QN / NPART);
    const float im0 = img[b * 4 + 0], im1 = img[b * 4 + 1], im2 = img[b * 4 + 2], im3 = img[b * 4 + 3];

    float GG0[NCOL], GG1[NCOL], GG2[NCOL], GG3[NCOL];
    float GN0[NCOL], GN1[NCOL], GN2[NCOL], GN3[NCOL];
    float TT0[NCOL], TT1[NCOL], TT2[NCOL];
    float RR0[NCOL], RR1[NCOL], RR2[NCOL];
    const float* CR[NCOL];
    float* CW[NCOL];
#pragma unroll
    for (int c = 0; c < NCOL; c++) {
        const int j = j0 + c;
        const float* g = gtb + ((size_t)(b * GN + j)) * 4;
        GG0[c] = g[0]; GG1[c] = g[1]; GG2[c] = g[2]; GG3[c] = g[3];
        const float* it = imgt + ((size_t)(b * GN + j)) * 4;
        GN0[c] = GG0[c] / it[0]; GN1[c] = GG1[c] / it[1];
        GN2[c] = GG2[c] / it[2]; GN3[c] = GG3[c] / it[3];
        TT0[c] = gtt[(b * GN + j) * 3 + 0]; TT1[c] = gtt[(b * GN + j) * 3 + 1]; TT2[c] = gtt[(b * GN + j) * 3 + 2];
        RR0[c] = gtr[(b * GN + j) * 3 + 0]; RR1[c] = gtr[(b * GN + j) * 3 + 1]; RR2[c] = gtr[(b * GN + j) * 3 + 2];
        const int lab = labels[b * GN + j];
        CR[c] = ccls + ((size_t)b * CN + lab) * QN;
        CW[c] = cost + ((size_t)(b * GN + j)) * QN;
    }

    float cv[NCOL][5]; int ci[NCOL][5]; float iv[NCOL][5];
#pragma unroll
    for (int c = 0; c < NCOL; c++)
#pragma unroll
        for (int k = 0; k < 5; k++) { cv[c][k] = FLT_MAX; ci[c][k] = INT_MAX; iv[c][k] = -1.0f; }

    for (int kk = 0; kk < QN / NPART / 256; kk++) {
        const int i = ibase + kk * 256 + t;
        const float4 bx = *reinterpret_cast<const float4*>(pboxes + ((size_t)(b * QN + i)) * 4);
        const float b0 = bx.x, b1 = bx.y, b2 = bx.z, b3 = bx.w;
        const float2* pp2 = reinterpret_cast<const float2*>(pposes + ((size_t)(b * QN + i)) * 6);
        const float2 q0 = pp2[0], q1 = pp2[1], q2 = pp2[2];
        const float p0 = q0.x, p1 = q0.y, p2 = q1.x, p3 = q1.y, p4 = q2.x, p5 = q2.y;
        const float fgadd = fg[(size_t)b * QN + i] ? 0.0f : 10000.0f;

        // row-common (bit-identical hoists)
        const float bn0 = b0 / im0, bn1 = b1 / im1, bn2 = b2 / im2, bn3 = b3 / im3;
        const float a1 = (b2 - b0) * (b3 - b1);
        const float ax = (b0 + b2) * 0.5f, ay = (b1 + b3) * 0.5f;

#pragma unroll
        for (int c = 0; c < NCOL; c++) {
            const float g0 = GG0[c], g1 = GG1[c], g2 = GG2[c], g3 = GG3[c];
            const float cc = CR[c][i];

            float ga = (g2 - g0) * (g3 - g1);
            float ltx = fmaxf(b0, g0), lty = fmaxf(b1, g1);
            float rbx = fminf(b2, g2), rby = fminf(b3, g3);
            float w = fmaxf(rbx - ltx, 0.0f), h = fmaxf(rby - lty, 0.0f);
            float inter = w * h;
            float uni = (a1 + ga) - inter;
            float iou = inter / uni;
            float eltx = fminf(b0, g0), elty = fminf(b1, g1);
            float erbx = fmaxf(b2, g2), erby = fmaxf(b3, g3);
            float ew = fmaxf(erbx - eltx, 0.0f), eh = fmaxf(erby - elty, 0.0f);
            float earea = ew * eh;
            float giou = iou - (earea - uni) / earea;

            float cb = fabsf(bn0 - GN0[c]);
            cb = cb + fabsf(bn1 - GN1[c]);
            cb = cb + fabsf(bn2 - GN2[c]);
            cb = cb + fabsf(bn3 - GN3[c]);
            float ct = fabsf(p0 - TT0[c]); ct = ct + fabsf(p1 - TT1[c]); ct = ct + fabsf(p2 - TT2[c]);
            float cr = fabsf(p3 - RR0[c]); cr = cr + fabsf(p4 - RR1[c]); cr = cr + fabsf(p5 - RR2[c]);

            float gcx = (g0 + g2) * 0.5f, gcy = (g1 + g3) * 0.5f;
            float gw = g2 - g0, gh = g3 - g1;
            float X0 = gcx - gw * 0.5f, Y0 = gcy - gh * 0.5f;
            float X1 = gcx + gw * 0.5f, Y1 = gcy + gh * 0.5f;
            float Wd = X1 - X0, Hd = Y1 - Y0;
            float LOX = gcx - 2.5f * Wd, HIX = gcx + 2.5f * Wd;
            float LOY = gcy - 2.5f * Hd, HIY = gcy + 2.5f * Hd;
            bool ib = (ax > X0) && (ax < X1) && (ay > Y0) && (ay < Y1);
            bool ic = (ax > LOX) && (ax < HIX) && (ay > LOY) && (ay < HIY);
            bool nb = !(ib && ic);

            float d = 5.0f * cb;
            d = d + 2.0f * cc;
            d = d + 2.0f * (-giou);
            d = d + (nb ? 100.0f : 0.0f);
            d = d + ct;
            d = d + cr;
            d = d + fgadd;

            CW[c][i] = d;

            // bottom-5 (cost,i): static cascade
            if (lexLessF(d, i, cv[c][4], ci[c][4])) {
                float dv = d; int di = i;
#pragma unroll
                for (int k = 0; k < 5; k++) {
                    bool sw = lexLessF(dv, di, cv[c][k], ci[c][k]);
                    float tv = sw ? cv[c][k] : dv; int ti = sw ? ci[c][k] : di;
                    cv[c][k] = sw ? dv : cv[c][k]; ci[c][k] = sw ? di : ci[c][k];
                    dv = tv; di = ti;
                }
            }
            // top-5 iou: static cascade (descending)
            if (iou > iv[c][4]) {
                float fv = iou;
#pragma unroll
                for (int k = 0; k < 5; k++) {
                    bool sw = fv > iv[c][k];
                    float tv = sw ? iv[c][k] : fv;
                    iv[c][k] = sw ? fv : iv[c][k];
                    fv = tv;
                }
            }
        }
    }

    __shared__ float scv[256 * 5];
    __shared__ int sci[256 * 5];
    __shared__ float siv[256 * 5];

    for (int c = 0; c < NCOL; c++) {
        __syncthreads();
#pragma unroll
        for (int k = 0; k < 5; k++) { scv[t * 5 + k] = cv[c][k]; sci[t * 5 + k] = ci[c][k]; siv[t * 5 + k] = iv[c][k]; }

        for (int s = 128; s > 0; s >>= 1) {
            __syncthreads();
            if (t < s) {
                float rv[5]; int ri[5]; float fr[5];
#pragma unroll
                for (int k = 0; k < 5; k++) { rv[k] = scv[t * 5 + k]; ri[k] = sci[t * 5 + k]; fr[k] = siv[t * 5 + k]; }
#pragma unroll
                for (int m = 0; m < 5; m++) {
                    float dv = scv[(t + s) * 5 + m]; int di = sci[(t + s) * 5 + m];
                    if (lexLessF(dv, di, rv[4], ri[4])) {
#pragma unroll
                        for (int k = 0; k < 5; k++) {
                            bool sw = lexLessF(dv, di, rv[k], ri[k]);
                            float tv = sw ? rv[k] : dv; int ti = sw ? ri[k] : di;
                            rv[k] = sw ? dv : rv[k]; ri[k] = sw ? di : ri[k];
                            dv = tv; di = ti;
                        }
                    }
                    float fv = siv[(t + s) * 5 + m];
                    if (fv > fr[4]) {
#pragma unroll
                        for (int k = 0; k < 5; k++) {
                            bool sw = fv > fr[k];
                            float tv = sw ? fr[k] : fv;
                            fr[k] = sw ? fv : fr[k];
                            fv = tv;
                        }
                    }
                }
#pragma unroll
                for (int k = 0; k < 5; k++) { scv[t * 5 + k] = rv[k]; sci[t * 5 + k] = ri[k]; siv[t * 5 + k] = fr[k]; }
            }
        }
        __syncthreads();
        if (t == 0) {
            const int col = b * GN + j0 + c;
#pragma unroll
            for (int k = 0; k < 5; k++) {
                pcv[((size_t)col * NPART + part) * 5 + k] = scv[k];
                pci[((size_t)col * NPART + part) * 5 + k] = sci[k];
                piv[((size_t)col * NPART + part) * 5 + k] = siv[k];
            }
        }
    }
}

// ---------------- merge parts, compute dk, set rowmask, save candidates ----------------
__global__ __launch_bounds__(256) void k_dk(const float* __restrict__ pcv,
                                            const int* __restrict__ pci,
                                            const float* __restrict__ piv,
                                            float* __restrict__ candcv, int* __restrict__ candci,
                                            int* __restrict__ dkArr, u64* __restrict__ rowmask) {
#pragma clang fp contract(off)
    const int b = blockIdx.x;
    const int j = threadIdx.x;
    const int col = b * GN + j;
    const float* pc = pcv + (size_t)col * NPART * 5;
    const int* pi = pci + (size_t)col * NPART * 5;
    const float* pv = piv + (size_t)col * NPART * 5;
    float rv[5]; int ri[5]; float fr[5];
#pragma unroll
    for (int k = 0; k < 5; k++) { rv[k] = pc[k]; ri[k] = pi[k]; fr[k] = pv[k]; }
    for (int p = 1; p < NPART; p++) {
#pragma unroll
        for (int m = 0; m < 5; m++) {
            float dv = pc[p * 5 + m]; int di = pi[p * 5 + m];
            if (lexLessF(dv, di, rv[4], ri[4])) {
#pragma unroll
                for (int k = 0; k < 5; k++) {
                    bool sw = lexLessF(dv, di, rv[k], ri[k]);
                    float tv = sw ? rv[k] : dv; int ti = sw ? ri[k] : di;
                    rv[k] = sw ? dv : rv[k]; ri[k] = sw ? di : ri[k];
                    dv = tv; di = ti;
                }
            }
            float fv = pv[p * 5 + m];
            if (fv > fr[4]) {
#pragma unroll
                for (int k = 0; k < 5; k++) {
                    bool sw = fv > fr[k];
                    float tv = sw ? fr[k] : fv;
                    fr[k] = sw ? fv : fr[k];
                    fv = tv;
                }
            }
        }
    }
    float sum = ((((fr[0] + fr[1]) + fr[2]) + fr[3]) + fr[4]);  // desc order, sequential
    int dk = (int)sum;
    if (dk < 1) dk = 1;
    if (dk > 5) dk = 5;
    dkArr[col] = dk;
#pragma unroll
    for (int k = 0; k < 5; k++) { candcv[(size_t)col * 5 + k] = rv[k]; candci[(size_t)col * 5 + k] = ri[k]; }
    for (int k = 0; k < dk; k++) {
        int i = ri[k];
        atomicOr(&rowmask[((size_t)(b * QN + i)) * 4 + (j >> 6)], 1ull << (j & 63));
    }
}

// ---------------- stale detect + pen + colcnt (non-stale rows) ----------------
__global__ __launch_bounds__(256) void k_stalepen(u64* __restrict__ rowmask,
                                                  unsigned char* __restrict__ pen,
                                                  int* __restrict__ colcnt,
                                                  int* __restrict__ staleCount,
                                                  int* __restrict__ staleList) {
    int b = blockIdx.y;
    int i = blockIdx.x * 256 + threadIdx.x;
    u64* rm = rowmask + ((size_t)(b * QN + i)) * 4;
    u64 w0 = rm[0], w1 = rm[1], w2 = rm[2], w3 = rm[3];
    int cnt = __popcll(w0) + __popcll(w1) + __popcll(w2) + __popcll(w3);
    pen[(size_t)b * QN + i] = (cnt > 0) ? 1 : 0;
    if (cnt > 1) {
        int idx = atomicAdd(staleCount, 1);
        staleList[idx] = (b << 12) | i;
    } else if (cnt == 1) {
        u64 w; int base;
        if (w0) { w = w0; base = 0; }
        else if (w1) { w = w1; base = 64; }
        else if (w2) { w = w2; base = 128; }
        else { w = w3; base = 192; }
        int j = base + (__ffsll((long long)w) - 1);
        atomicAdd(&colcnt[b * GN + j], 1);
    }
}

// ---------------- stale fix: row -> one_hot(argmin_j cost); record bj ----------------
__global__ __launch_bounds__(256) void k_stalefix(const float* __restrict__ cost,
                                                  u64* __restrict__ rowmask,
                                                  int* __restrict__ colcnt,
                                                  const int* __restrict__ staleCount,
                                                  const int* __restrict__ staleList,
                                                  int* __restrict__ fixBj) {
    int gtid = blockIdx.x * blockDim.x + threadIdx.x;
    int wid = gtid >> 6;
    int lane = threadIdx.x & 63;
    int nw = (gridDim.x * blockDim.x) >> 6;
    int n = *staleCount;
    for (int e = wid; e < n; e += nw) {
        int pk = staleList[e];
        int b = pk >> 12, i = pk & 4095;
        const float* cb = cost + (size_t)b * GN * QN + i;
        float best = FLT_MAX; int bj = GN;
        for (int k = 0; k < GN; k += 64) {
            int j = k + lane;
            float v = cb[(size_t)j * QN];
            if (lexLessF(v, j, best, bj)) { best = v; bj = j; }
        }
        for (int off = 32; off > 0; off >>= 1) {
            float ov = __shfl_down(best, off, 64);
            int oj = __shfl_down(bj, off, 64);
            if (lexLessF(ov, oj, best, bj)) { best = ov; bj = oj; }
        }
        if (lane == 0) {
            u64* rm = rowmask + ((size_t)(b * QN + i)) * 4;
            rm[0] = ((bj >> 6) == 0) ? (1ull << (bj & 63)) : 0ull;
            rm[1] = ((bj >> 6) == 1) ? (1ull << (bj & 63)) : 0ull;
            rm[2] = ((bj >> 6) == 2) ? (1ull << (bj & 63)) : 0ull;
            rm[3] = ((bj >> 6) == 3) ? (1ull << (bj & 63)) : 0ull;
            atomicAdd(&colcnt[b * GN + bj], 1);
            fixBj[e] = bj;
        }
    }
}

// ---------------- assign unmatched columns to cheapest unmatched row (exact f32) ----------------
__global__ __launch_bounds__(256) void k_assign(const float* __restrict__ cost,
                                                const unsigned char* __restrict__ pen,
                                                const int* __restrict__ colcnt,
                                                u64* __restrict__ rowmask,
                                                int* __restrict__ assign) {
    int b = blockIdx.x >> 8, j = blockIdx.x & 255;
    if (colcnt[b * GN + j] != 0) {
        if (threadIdx.x == 0) assign[b * GN + j] = -1;
        return;
    }
    const float* cc = cost + ((size_t)(b * GN + j)) * QN;
    const unsigned char* pp = pen + (size_t)b * QN;
    float best = FLT_MAX; int bi = INT_MAX;
    for (int k = threadIdx.x; k < QN; k += 256) {
        if (!pp[k]) {
            float v = cc[k];
            if (lexLessF(v, k, best, bi)) { best = v; bi = k; }
        }
    }
    __shared__ float sv[256];
    __shared__ int si[256];
    sv[threadIdx.x] = best; si[threadIdx.x] = bi;
    for (int s = 128; s > 0; s >>= 1) {
        __syncthreads();
        if (threadIdx.x < s) {
            float ov = sv[threadIdx.x + s]; int oi = si[threadIdx.x + s];
            if (lexLessF(ov, oi, sv[threadIdx.x], si[threadIdx.x])) {
                sv[threadIdx.x] = ov; si[threadIdx.x] = oi;
            }
        }
    }
    if (threadIdx.x == 0) {
        int r = si[0];
        assign[b * GN + j] = r;
        atomicOr(&rowmask[((size_t)(b * QN + r)) * 4 + (j >> 6)], 1ull << (j & 63));
    }
}

// ---------------- per-row outputs: selected, gt_idx ----------------
__global__ __launch_bounds__(256) void k_outrows(const u64* __restrict__ rowmask,
                                                 int* __restrict__ out) {
    int b = blockIdx.y;
    int i = blockIdx.x * 256 + threadIdx.x;
    const u64* rm = rowmask + ((size_t)(b * QN + i)) * 4;
    u64 w0 = rm[0], w1 = rm[1], w2 = rm[2], w3 = rm[3];
    int sel = (w0 | w1 | w2 | w3) ? 1 : 0;
    int g = 0;
    if (w0) g = __ffsll((long long)w0) - 1;
    else if (w1) g = 64 + __ffsll((long long)w1) - 1;
    else if (w2) g = 128 + __ffsll((long long)w2) - 1;
    else if (w3) g = 192 + __ffsll((long long)w3) - 1;
    out[(size_t)b * QN + i] = sel;
    out[(size_t)BN * QN + (size_t)b * QN + i] = g;
}

// ---------------- per-column output: matched_qidx (candidate-based, no scan) ----
// Matched rows of a non-assigned column j are exactly:
//   {dk candidates (k<dk) whose rowmask bit j survived} U {stale rows with fixBj==j}.
// Compare f32(cost+100000) with index tiebreak -- identical comparator/set to the
// previous full-scan version.
__global__ __launch_bounds__(256) void k_outcols(const float* __restrict__ cost,
                                                 const u64* __restrict__ rowmask,
                                                 const int* __restrict__ assign,
                                                 const float* __restrict__ candcv,
                                                 const int* __restrict__ candci,
                                                 const int* __restrict__ dkArr,
                                                 const int* __restrict__ staleCount,
                                                 const int* __restrict__ staleList,
                                                 const int* __restrict__ fixBj,
                                                 int* __restrict__ out) {
    const int b = blockIdx.x;
    const int j = threadIdx.x;
    const int col = b * GN + j;
    int* o = out + (size_t)2 * BN * QN + col;
    int a = assign[col];
    if (a >= 0) { *o = a; return; }
    const u64 bit = 1ull << (j & 63);
    const int w = j >> 6;
    float best = FLT_MAX; int bi = INT_MAX;
    const int dk = dkArr[col];
    for (int k = 0; k < 5; k++) {
        if (k < dk) {
            int i = candci[(size_t)col * 5 + k];
            if (rowmask[((size_t)(b * QN + i)) * 4 + w] & bit) {
                float pv = candcv[(size_t)col * 5 + k] + 100000.0f;
                if (lexLessF(pv, i, best, bi)) { best = pv; bi = i; }
            }
        }
    }
    const int n = *staleCount;
    for (int e = 0; e < n; e++) {
        int pk = staleList[e];
        int eb = pk >> 12, ei = pk & 4095;
        if (eb == b && fixBj[e] == j) {
            float pv = cost[(size_t)col * QN + ei] + 100000.0f;
            if (lexLessF(pv, ei, best, bi)) { best = pv; bi = ei; }
        }
    }
    *o = (bi == INT_MAX) ? 0 : bi;
}

extern "C" void kernel_launch(void* const* d_in, const int* in_sizes, int n_in,
                              void* d_out, int out_size, void* d_ws, size_t ws_size,
                              hipStream_t stream) {
    const float* logits = (const float*)d_in[0];
    const float* pboxes = (const float*)d_in[1];
    const float* pposes = (const float*)d_in[2];
    const int* labels = (const int*)d_in[3];
    const float* gtb = (const float*)d_in[4];
    const float* gtt = (const float*)d_in[5];
    const float* gtr = (const float*)d_in[6];
    const float* img = (const float*)d_in[7];
    const float* imgt = (const float*)d_in[8];
    int* out = (int*)d_out;

    char* p = (char*)d_ws;
    float* cost = (float*)p;             p += (size_t)BN * GN * QN * 4;      // 64 MiB
    float* ccls = (float*)p;             p += (size_t)BN * CN * QN * 4;      // 20 MiB
    u64* rowmask = (u64*)p;              size_t rb = (size_t)BN * QN * 4 * 8; p += rb;  // 2 MiB
    int* colcnt = (int*)p;               p += (size_t)BN * GN * 4;            // 16 KiB
    int* staleCount = (int*)p;           p += 64;
    int* staleList = (int*)p;            p += (size_t)BN * QN * 4;            // 256 KiB
    int* fixBj = (int*)p;                p += (size_t)BN * QN * 4;            // 256 KiB
    unsigned char* pen = (unsigned char*)p; p += (size_t)BN * QN;             // 64 KiB
    unsigned char* fg = (unsigned char*)p;  p += (size_t)BN * QN;             // 64 KiB
    int* assign = (int*)p;               p += (size_t)BN * GN * 4;            // 16 KiB
    float* pcv = (float*)p;              p += (size_t)BN * GN * NPART * 5 * 4;  // 320 KiB
    int* pci = (int*)p;                  p += (size_t)BN * GN * NPART * 5 * 4;  // 320 KiB
    float* piv = (float*)p;              p += (size_t)BN * GN * NPART * 5 * 4;  // 320 KiB
    float* candcv = (float*)p;           p += (size_t)BN * GN * 5 * 4;          // 80 KiB
    int* candci = (int*)p;               p += (size_t)BN * GN * 5 * 4;          // 80 KiB
    int* dkArr = (int*)p;                p += (size_t)BN * GN * 4;              // 16 KiB

    // zero rowmask + colcnt + staleCount (contiguous)
    int zn = (int)((rb + (size_t)BN * GN * 4 + 64) / 8);
    k_zero<<<(zn + 255) / 256, 256, 0, stream>>>(rowmask, zn);

    k_class<<<BN * 64, 256, 0, stream>>>(logits, ccls);
    k_fg<<<dim3(QN / 256, BN), 256, 0, stream>>>(gtb, pboxes, fg);
    k_cost<<<BN * (GN / NCOL) * NPART, 256, 0, stream>>>(ccls, pboxes, pposes, labels, gtb, gtt, gtr,
                                                         img, imgt, fg, cost, pcv, pci, piv);
    k_dk<<<BN, 256, 0, stream>>>(pcv, pci, piv, candcv, candci, dkArr, rowmask);
    k_stalepen<<<dim3(QN / 256, BN), 256, 0, stream>>>(rowmask, pen, colcnt, staleCount, staleList);
    k_stalefix<<<256, 256, 0, stream>>>(cost, rowmask, colcnt, staleCount, staleList, fixBj);
    k_assign<<<BN * GN, 256, 0, stream>>>(cost, pen, colcnt, rowmask, assign);
    k_outrows<<<dim3(QN / 256, BN), 256, 0, stream>>>(rowmask, out);
    k_outcols<<<BN, 256, 0, stream>>>(cost, rowmask, assign, candcv, candci, dkArr,
                                      staleCount, staleList, fixBj, out);
}

// Round 8
// 383.335 us; speedup vs baseline: 1.9766x; 1.9766x over previous
//
#include <hip/hip_runtime.h>
#include <cfloat>
#include <climits>
#include <math.h>

#define BN 16
#define QN 4096
#define GN 256
#define CN 80
#define NJP 8              // column strips in k_cost
#define JPB (GN / NJP)     // 32 columns per block
#define PSTR 32            // param stride (floats)

typedef unsigned long long u64;

__device__ __forceinline__ bool lexLessF(float a, int ia, float b, int ib) {
    return (a < b) || (a == b && ia < ib);
}

// ---------------- zero init (rowmask + colcnt + staleCount) ----------------
__global__ void k_zero(u64* __restrict__ p, int n) {
    int i = blockIdx.x * blockDim.x + threadIdx.x;
    if (i < n) p[i] = 0ull;
}

// ---------------- focal class-cost table + per-column param table ----------------
// ccls[b][c][i]; blocks with iblk==0 additionally build prm[b][j][PSTR].
__global__ __launch_bounds__(256) void k_class(const float* __restrict__ logits,
                                               const float* __restrict__ gtb,
                                               const float* __restrict__ gtt,
                                               const float* __restrict__ gtr,
                                               const float* __restrict__ imgt,
                                               float* __restrict__ ccls,
                                               float* __restrict__ prm) {
#pragma clang fp contract(off)
    const int b = blockIdx.x >> 6, iblk = blockIdx.x & 63;
    const int lane = threadIdx.x & 63, cg = threadIdx.x >> 6;  // 4 c-groups x 20
    const int i = iblk * 64 + lane;
    const float* lrow = logits + ((size_t)(b * QN + i)) * CN + cg * 20;
    // 20 classes via 5 float4 loads (16B-aligned: row stride 320B, cg*80B)
#pragma unroll
    for (int q = 0; q < 5; q++) {
        const float4 xv = *reinterpret_cast<const float4*>(lrow + q * 4);
        float xs[4] = {xv.x, xv.y, xv.z, xv.w};
#pragma unroll
        for (int u = 0; u < 4; u++) {
            float x = xs[u];
            float e = (float)exp(-(double)x);
            float pr = 1.0f / (1.0f + e);
            float om = 1.0f - pr;
            float lneg = (float)log((double)(om + 1e-8f));
            float lpos = (float)log((double)(pr + 1e-8f));
            float neg = (0.75f * (pr * pr)) * (-lneg);
            float pos = (0.25f * (om * om)) * (-lpos);
            int c = cg * 20 + q * 4 + u;
            ccls[((size_t)b * CN + c) * QN + i] = pos - neg;
        }
    }
    if (iblk == 0) {
        const int j = threadIdx.x;
        const float* g = gtb + ((size_t)(b * GN + j)) * 4;
        const float g0 = g[0], g1 = g[1], g2 = g[2], g3 = g[3];
        const float* it = imgt + ((size_t)(b * GN + j)) * 4;
        float* P = prm + (size_t)(b * GN + j) * PSTR;
        P[0] = g0; P[1] = g1; P[2] = g2; P[3] = g3;
        P[4] = g0 / it[0]; P[5] = g1 / it[1]; P[6] = g2 / it[2]; P[7] = g3 / it[3];
        P[8] = gtt[(b * GN + j) * 3 + 0]; P[9] = gtt[(b * GN + j) * 3 + 1]; P[10] = gtt[(b * GN + j) * 3 + 2];
        P[11] = gtr[(b * GN + j) * 3 + 0]; P[12] = gtr[(b * GN + j) * 3 + 1]; P[13] = gtr[(b * GN + j) * 3 + 2];
        P[14] = (g2 - g0) * (g3 - g1);   // ga
        // box-test bounds (same op sequence as reference)
        float gcx = (g0 + g2) * 0.5f, gcy = (g1 + g3) * 0.5f;
        float gw = g2 - g0, gh = g3 - g1;
        float X0 = gcx - gw * 0.5f, Y0 = gcy - gh * 0.5f;
        float X1 = gcx + gw * 0.5f, Y1 = gcy + gh * 0.5f;
        float Wd = X1 - X0, Hd = Y1 - Y0;
        P[15] = X0; P[16] = Y0; P[17] = X1; P[18] = Y1;
        P[19] = gcx - 2.5f * Wd; P[20] = gcx + 2.5f * Wd;
        P[21] = gcy - 2.5f * Hd; P[22] = gcy + 2.5f * Hd;
    }
}

// ---------------- fg per query row (f32, exact reference order) ----------------
__global__ __launch_bounds__(256) void k_fg(const float* __restrict__ gtb,
                                            const float* __restrict__ pb,
                                            unsigned char* __restrict__ fg) {
#pragma clang fp contract(off)
    int b = blockIdx.y;
    int i = blockIdx.x * 256 + threadIdx.x;
    __shared__ float s[GN][8];
    for (int j = threadIdx.x; j < GN; j += 256) {
        const float* g = gtb + ((size_t)(b * GN + j)) * 4;
        float g0 = g[0], g1 = g[1], g2 = g[2], g3 = g[3];
        float gcx = (g0 + g2) * 0.5f, gcy = (g1 + g3) * 0.5f;
        float gw = g2 - g0, gh = g3 - g1;
        float x0 = gcx - gw * 0.5f, y0 = gcy - gh * 0.5f;
        float x1 = gcx + gw * 0.5f, y1 = gcy + gh * 0.5f;
        float w = x1 - x0, h = y1 - y0;
        s[j][0] = x0; s[j][1] = y0; s[j][2] = x1; s[j][3] = y1;
        s[j][4] = gcx - 2.5f * w; s[j][5] = gcx + 2.5f * w;
        s[j][6] = gcy - 2.5f * h; s[j][7] = gcy + 2.5f * h;
    }
    __syncthreads();
    const float4 bb = *reinterpret_cast<const float4*>(pb + ((size_t)(b * QN + i)) * 4);
    float ax = (bb.x + bb.z) * 0.5f, ay = (bb.y + bb.w) * 0.5f;
    bool anyib = false, anyic = false;
    for (int j = 0; j < GN; j++) {
        bool ib = (ax > s[j][0]) && (ax < s[j][2]) && (ay > s[j][1]) && (ay < s[j][3]);
        bool ic = (ax > s[j][4]) && (ax < s[j][5]) && (ay > s[j][6]) && (ay < s[j][7]);
        anyib |= ib; anyic |= ic;
    }
    fg[(size_t)b * QN + i] = (anyib || anyic) ? 1 : 0;
}

// ---------------- cost matrix: pure streaming, NO selection ----------------
// Block = (b, 256-row tile, 32-column strip). Row data in registers once;
// column params via uniform loads from prm. Inner loop: 1 gather + 1 store.
__global__ __launch_bounds__(256) void k_cost(
    const float* __restrict__ ccls, const float* __restrict__ pboxes,
    const float* __restrict__ pposes, const int* __restrict__ labels,
    const float* __restrict__ prm, const float* __restrict__ img,
    const unsigned char* __restrict__ fg, float* __restrict__ cost) {
#pragma clang fp contract(off)
    const int t = threadIdx.x;
    const int b = blockIdx.x >> 7;
    const int rem = blockIdx.x & 127;
    const int itile = rem >> 3, jp = rem & 7;
    const int i = itile * 256 + t;
    const int j0 = jp * JPB;

    const float im0 = img[b * 4 + 0], im1 = img[b * 4 + 1], im2 = img[b * 4 + 2], im3 = img[b * 4 + 3];
    const float4 bx = *reinterpret_cast<const float4*>(pboxes + ((size_t)(b * QN + i)) * 4);
    const float b0 = bx.x, b1 = bx.y, b2 = bx.z, b3 = bx.w;
    const float2* pp2 = reinterpret_cast<const float2*>(pposes + ((size_t)(b * QN + i)) * 6);
    const float2 q0 = pp2[0], q1 = pp2[1], q2 = pp2[2];
    const float p0 = q0.x, p1 = q0.y, p2 = q1.x, p3 = q1.y, p4 = q2.x, p5 = q2.y;
    const float fgadd = fg[(size_t)b * QN + i] ? 0.0f : 10000.0f;

    // row-common (bit-identical hoists, verified r6/r7)
    const float bn0 = b0 / im0, bn1 = b1 / im1, bn2 = b2 / im2, bn3 = b3 / im3;
    const float a1 = (b2 - b0) * (b3 - b1);
    const float ax = (b0 + b2) * 0.5f, ay = (b1 + b3) * 0.5f;

    for (int jj = 0; jj < JPB; jj++) {
        const int j = j0 + jj;
        const float* P = prm + (size_t)(b * GN + j) * PSTR;   // uniform -> scalar loads
        const float g0 = P[0], g1 = P[1], g2 = P[2], g3 = P[3];
        const float cc = ccls[((size_t)b * CN + labels[b * GN + j]) * QN + i];

        // iou / giou (f32, reference op order)
        float ga = P[14];
        float ltx = fmaxf(b0, g0), lty = fmaxf(b1, g1);
        float rbx = fminf(b2, g2), rby = fminf(b3, g3);
        float w = fmaxf(rbx - ltx, 0.0f), h = fmaxf(rby - lty, 0.0f);
        float inter = w * h;
        float uni = (a1 + ga) - inter;
        float iou = inter / uni;
        float eltx = fminf(b0, g0), elty = fminf(b1, g1);
        float erbx = fmaxf(b2, g2), erby = fmaxf(b3, g3);
        float ew = fmaxf(erbx - eltx, 0.0f), eh = fmaxf(erby - elty, 0.0f);
        float earea = ew * eh;
        float giou = iou - (earea - uni) / earea;

        // normalized bbox L1 (sequential f32)
        float cb = fabsf(bn0 - P[4]);
        cb = cb + fabsf(bn1 - P[5]);
        cb = cb + fabsf(bn2 - P[6]);
        cb = cb + fabsf(bn3 - P[7]);
        // pose L1
        float ct = fabsf(p0 - P[8]); ct = ct + fabsf(p1 - P[9]); ct = ct + fabsf(p2 - P[10]);
        float cr = fabsf(p3 - P[11]); cr = cr + fabsf(p4 - P[12]); cr = cr + fabsf(p5 - P[13]);
        // both = in_box & in_ctr
        bool ib = (ax > P[15]) && (ax < P[17]) && (ay > P[16]) && (ay < P[18]);
        bool ic = (ax > P[19]) && (ax < P[20]) && (ay > P[21]) && (ay < P[22]);
        bool nb = !(ib && ic);

        float d = 5.0f * cb;
        d = d + 2.0f * cc;
        d = d + 2.0f * (-giou);
        d = d + (nb ? 100.0f : 0.0f);
        d = d + ct;
        d = d + cr;
        d = d + fgadd;

        cost[(size_t)(b * GN + j) * QN + i] = d;
    }
}

// ---------------- per-column selection: bottom-5 cost + top-5 iou + dk ----------------
// Reads cost column (contiguous) + recomputes iou (identical ops). Static cascades.
__global__ __launch_bounds__(256) void k_sel(const float* __restrict__ cost,
                                             const float* __restrict__ pboxes,
                                             const float* __restrict__ prm,
                                             float* __restrict__ candcv, int* __restrict__ candci,
                                             int* __restrict__ dkArr, u64* __restrict__ rowmask) {
#pragma clang fp contract(off)
    const int t = threadIdx.x;
    const int b = blockIdx.x >> 8, j = blockIdx.x & 255;
    const float* P = prm + (size_t)(b * GN + j) * PSTR;
    const float g0 = P[0], g1 = P[1], g2 = P[2], g3 = P[3], ga = P[14];
    const float* cc = cost + (size_t)(b * GN + j) * QN;

    float cv[5]; int ci[5]; float iv[5];
#pragma unroll
    for (int k = 0; k < 5; k++) { cv[k] = FLT_MAX; ci[k] = INT_MAX; iv[k] = -1.0f; }

    for (int kk = 0; kk < QN / 256; kk++) {
        const int i = kk * 256 + t;
        const float d = cc[i];
        const float4 bx = *reinterpret_cast<const float4*>(pboxes + ((size_t)(b * QN + i)) * 4);
        const float b0 = bx.x, b1 = bx.y, b2 = bx.z, b3 = bx.w;
        float a1 = (b2 - b0) * (b3 - b1);
        float ltx = fmaxf(b0, g0), lty = fmaxf(b1, g1);
        float rbx = fminf(b2, g2), rby = fminf(b3, g3);
        float w = fmaxf(rbx - ltx, 0.0f), h = fmaxf(rby - lty, 0.0f);
        float inter = w * h;
        float uni = (a1 + ga) - inter;
        float iou = inter / uni;

        if (lexLessF(d, i, cv[4], ci[4])) {
            float dv = d; int di = i;
#pragma unroll
            for (int k = 0; k < 5; k++) {
                bool sw = lexLessF(dv, di, cv[k], ci[k]);
                float tv = sw ? cv[k] : dv; int ti = sw ? ci[k] : di;
                cv[k] = sw ? dv : cv[k]; ci[k] = sw ? di : ci[k];
                dv = tv; di = ti;
            }
        }
        if (iou > iv[4]) {
            float fv = iou;
#pragma unroll
            for (int k = 0; k < 5; k++) {
                bool sw = fv > iv[k];
                float tv = sw ? iv[k] : fv;
                iv[k] = sw ? fv : iv[k];
                fv = tv;
            }
        }
    }

    __shared__ float scv[256 * 5];
    __shared__ int sci[256 * 5];
    __shared__ float siv[256 * 5];
#pragma unroll
    for (int k = 0; k < 5; k++) { scv[t * 5 + k] = cv[k]; sci[t * 5 + k] = ci[k]; siv[t * 5 + k] = iv[k]; }

    for (int s = 128; s > 0; s >>= 1) {
        __syncthreads();
        if (t < s) {
            float rv[5]; int ri[5]; float fr[5];
#pragma unroll
            for (int k = 0; k < 5; k++) { rv[k] = scv[t * 5 + k]; ri[k] = sci[t * 5 + k]; fr[k] = siv[t * 5 + k]; }
#pragma unroll
            for (int m = 0; m < 5; m++) {
                float dv = scv[(t + s) * 5 + m]; int di = sci[(t + s) * 5 + m];
                if (lexLessF(dv, di, rv[4], ri[4])) {
#pragma unroll
                    for (int k = 0; k < 5; k++) {
                        bool sw = lexLessF(dv, di, rv[k], ri[k]);
                        float tv = sw ? rv[k] : dv; int ti = sw ? ri[k] : di;
                        rv[k] = sw ? dv : rv[k]; ri[k] = sw ? di : ri[k];
                        dv = tv; di = ti;
                    }
                }
                float fv = siv[(t + s) * 5 + m];
                if (fv > fr[4]) {
#pragma unroll
                    for (int k = 0; k < 5; k++) {
                        bool sw = fv > fr[k];
                        float tv = sw ? fr[k] : fv;
                        fr[k] = sw ? fv : fr[k];
                        fv = tv;
                    }
                }
            }
#pragma unroll
            for (int k = 0; k < 5; k++) { scv[t * 5 + k] = rv[k]; sci[t * 5 + k] = ri[k]; siv[t * 5 + k] = fr[k]; }
        }
    }
    __syncthreads();
    if (t == 0) {
        float sum = ((((siv[0] + siv[1]) + siv[2]) + siv[3]) + siv[4]);  // desc order
        int dk = (int)sum;
        if (dk < 1) dk = 1;
        if (dk > 5) dk = 5;
        const int col = b * GN + j;
        dkArr[col] = dk;
#pragma unroll
        for (int k = 0; k < 5; k++) { candcv[(size_t)col * 5 + k] = scv[k]; candci[(size_t)col * 5 + k] = sci[k]; }
        for (int k = 0; k < dk; k++) {
            int i = sci[k];
            atomicOr(&rowmask[((size_t)(b * QN + i)) * 4 + (j >> 6)], 1ull << (j & 63));
        }
    }
}

// ---------------- stale detect + pen + colcnt (non-stale rows) ----------------
__global__ __launch_bounds__(256) void k_stalepen(u64* __restrict__ rowmask,
                                                  unsigned char* __restrict__ pen,
                                                  int* __restrict__ colcnt,
                                                  int* __restrict__ staleCount,
                                                  int* __restrict__ staleList) {
    int b = blockIdx.y;
    int i = blockIdx.x * 256 + threadIdx.x;
    u64* rm = rowmask + ((size_t)(b * QN + i)) * 4;
    u64 w0 = rm[0], w1 = rm[1], w2 = rm[2], w3 = rm[3];
    int cnt = __popcll(w0) + __popcll(w1) + __popcll(w2) + __popcll(w3);
    pen[(size_t)b * QN + i] = (cnt > 0) ? 1 : 0;
    if (cnt > 1) {
        int idx = atomicAdd(staleCount, 1);
        staleList[idx] = (b << 12) | i;
    } else if (cnt == 1) {
        u64 w; int base;
        if (w0) { w = w0; base = 0; }
        else if (w1) { w = w1; base = 64; }
        else if (w2) { w = w2; base = 128; }
        else { w = w3; base = 192; }
        int j = base + (__ffsll((long long)w) - 1);
        atomicAdd(&colcnt[b * GN + j], 1);
    }
}

// ---------------- stale fix: row -> one_hot(argmin_j cost); record bj ----------------
__global__ __launch_bounds__(256) void k_stalefix(const float* __restrict__ cost,
                                                  u64* __restrict__ rowmask,
                                                  int* __restrict__ colcnt,
                                                  const int* __restrict__ staleCount,
                                                  const int* __restrict__ staleList,
                                                  int* __restrict__ fixBj) {
    int gtid = blockIdx.x * blockDim.x + threadIdx.x;
    int wid = gtid >> 6;
    int lane = threadIdx.x & 63;
    int nw = (gridDim.x * blockDim.x) >> 6;
    int n = *staleCount;
    for (int e = wid; e < n; e += nw) {
        int pk = staleList[e];
        int b = pk >> 12, i = pk & 4095;
        const float* cb = cost + (size_t)b * GN * QN + i;
        float best = FLT_MAX; int bj = GN;
        for (int k = 0; k < GN; k += 64) {
            int j = k + lane;
            float v = cb[(size_t)j * QN];
            if (lexLessF(v, j, best, bj)) { best = v; bj = j; }
        }
        for (int off = 32; off > 0; off >>= 1) {
            float ov = __shfl_down(best, off, 64);
            int oj = __shfl_down(bj, off, 64);
            if (lexLessF(ov, oj, best, bj)) { best = ov; bj = oj; }
        }
        if (lane == 0) {
            u64* rm = rowmask + ((size_t)(b * QN + i)) * 4;
            rm[0] = ((bj >> 6) == 0) ? (1ull << (bj & 63)) : 0ull;
            rm[1] = ((bj >> 6) == 1) ? (1ull << (bj & 63)) : 0ull;
            rm[2] = ((bj >> 6) == 2) ? (1ull << (bj & 63)) : 0ull;
            rm[3] = ((bj >> 6) == 3) ? (1ull << (bj & 63)) : 0ull;
            atomicAdd(&colcnt[b * GN + bj], 1);
            fixBj[e] = bj;
        }
    }
}

// ---------------- assign unmatched columns to cheapest unmatched row ----------------
__global__ __launch_bounds__(256) void k_assign(const float* __restrict__ cost,
                                                const unsigned char* __restrict__ pen,
                                                const int* __restrict__ colcnt,
                                                u64* __restrict__ rowmask,
                                                int* __restrict__ assign) {
    int b = blockIdx.x >> 8, j = blockIdx.x & 255;
    if (colcnt[b * GN + j] != 0) {
        if (threadIdx.x == 0) assign[b * GN + j] = -1;
        return;
    }
    const float* cc = cost + ((size_t)(b * GN + j)) * QN;
    const unsigned char* pp = pen + (size_t)b * QN;
    float best = FLT_MAX; int bi = INT_MAX;
    for (int k = threadIdx.x; k < QN; k += 256) {
        if (!pp[k]) {
            float v = cc[k];
            if (lexLessF(v, k, best, bi)) { best = v; bi = k; }
        }
    }
    __shared__ float sv[256];
    __shared__ int si[256];
    sv[threadIdx.x] = best; si[threadIdx.x] = bi;
    for (int s = 128; s > 0; s >>= 1) {
        __syncthreads();
        if (threadIdx.x < s) {
            float ov = sv[threadIdx.x + s]; int oi = si[threadIdx.x + s];
            if (lexLessF(ov, oi, sv[threadIdx.x], si[threadIdx.x])) {
                sv[threadIdx.x] = ov; si[threadIdx.x] = oi;
            }
        }
    }
    if (threadIdx.x == 0) {
        int r = si[0];
        assign[b * GN + j] = r;
        atomicOr(&rowmask[((size_t)(b * QN + r)) * 4 + (j >> 6)], 1ull << (j & 63));
    }
}

// ---------------- per-row outputs: selected, gt_idx ----------------
__global__ __launch_bounds__(256) void k_outrows(const u64* __restrict__ rowmask,
                                                 int* __restrict__ out) {
    int b = blockIdx.y;
    int i = blockIdx.x * 256 + threadIdx.x;
    const u64* rm = rowmask + ((size_t)(b * QN + i)) * 4;
    u64 w0 = rm[0], w1 = rm[1], w2 = rm[2], w3 = rm[3];
    int sel = (w0 | w1 | w2 | w3) ? 1 : 0;
    int g = 0;
    if (w0) g = __ffsll((long long)w0) - 1;
    else if (w1) g = 64 + __ffsll((long long)w1) - 1;
    else if (w2) g = 128 + __ffsll((long long)w2) - 1;
    else if (w3) g = 192 + __ffsll((long long)w3) - 1;
    out[(size_t)b * QN + i] = sel;
    out[(size_t)BN * QN + (size_t)b * QN + i] = g;
}

// ---------------- per-column output: matched_qidx (candidate-based) ----------------
__global__ __launch_bounds__(256) void k_outcols(const float* __restrict__ cost,
                                                 const u64* __restrict__ rowmask,
                                                 const int* __restrict__ assign,
                                                 const float* __restrict__ candcv,
                                                 const int* __restrict__ candci,
                                                 const int* __restrict__ dkArr,
                                                 const int* __restrict__ staleCount,
                                                 const int* __restrict__ staleList,
                                                 const int* __restrict__ fixBj,
                                                 int* __restrict__ out) {
    const int b = blockIdx.x;
    const int j = threadIdx.x;
    const int col = b * GN + j;
    int* o = out + (size_t)2 * BN * QN + col;
    int a = assign[col];
    if (a >= 0) { *o = a; return; }
    const u64 bit = 1ull << (j & 63);
    const int w = j >> 6;
    float best = FLT_MAX; int bi = INT_MAX;
    const int dk = dkArr[col];
    for (int k = 0; k < 5; k++) {
        if (k < dk) {
            int i = candci[(size_t)col * 5 + k];
            if (rowmask[((size_t)(b * QN + i)) * 4 + w] & bit) {
                float pv = candcv[(size_t)col * 5 + k] + 100000.0f;
                if (lexLessF(pv, i, best, bi)) { best = pv; bi = i; }
            }
        }
    }
    const int n = *staleCount;
    for (int e = 0; e < n; e++) {
        int pk = staleList[e];
        int eb = pk >> 12, ei = pk & 4095;
        if (eb == b && fixBj[e] == j) {
            float pv = cost[(size_t)col * QN + ei] + 100000.0f;
            if (lexLessF(pv, ei, best, bi)) { best = pv; bi = ei; }
        }
    }
    *o = (bi == INT_MAX) ? 0 : bi;
}

extern "C" void kernel_launch(void* const* d_in, const int* in_sizes, int n_in,
                              void* d_out, int out_size, void* d_ws, size_t ws_size,
                              hipStream_t stream) {
    const float* logits = (const float*)d_in[0];
    const float* pboxes = (const float*)d_in[1];
    const float* pposes = (const float*)d_in[2];
    const int* labels = (const int*)d_in[3];
    const float* gtb = (const float*)d_in[4];
    const float* gtt = (const float*)d_in[5];
    const float* gtr = (const float*)d_in[6];
    const float* img = (const float*)d_in[7];
    const float* imgt = (const float*)d_in[8];
    int* out = (int*)d_out;

    char* p = (char*)d_ws;
    float* cost = (float*)p;             p += (size_t)BN * GN * QN * 4;      // 64 MiB
    float* ccls = (float*)p;             p += (size_t)BN * CN * QN * 4;      // 20 MiB
    u64* rowmask = (u64*)p;              size_t rb = (size_t)BN * QN * 4 * 8; p += rb;  // 2 MiB
    int* colcnt = (int*)p;               p += (size_t)BN * GN * 4;            // 16 KiB
    int* staleCount = (int*)p;           p += 64;
    int* staleList = (int*)p;            p += (size_t)BN * QN * 4;            // 256 KiB
    int* fixBj = (int*)p;                p += (size_t)BN * QN * 4;            // 256 KiB
    unsigned char* pen = (unsigned char*)p; p += (size_t)BN * QN;             // 64 KiB
    unsigned char* fg = (unsigned char*)p;  p += (size_t)BN * QN;             // 64 KiB
    int* assign = (int*)p;               p += (size_t)BN * GN * 4;            // 16 KiB
    float* prm = (float*)p;              p += (size_t)BN * GN * PSTR * 4;     // 512 KiB
    float* candcv = (float*)p;           p += (size_t)BN * GN * 5 * 4;        // 80 KiB
    int* candci = (int*)p;               p += (size_t)BN * GN * 5 * 4;        // 80 KiB
    int* dkArr = (int*)p;                p += (size_t)BN * GN * 4;            // 16 KiB

    // zero rowmask + colcnt + staleCount (contiguous)
    int zn = (int)((rb + (size_t)BN * GN * 4 + 64) / 8);
    k_zero<<<(zn + 255) / 256, 256, 0, stream>>>(rowmask, zn);

    k_class<<<BN * 64, 256, 0, stream>>>(logits, gtb, gtt, gtr, imgt, ccls, prm);
    k_fg<<<dim3(QN / 256, BN), 256, 0, stream>>>(gtb, pboxes, fg);
    k_cost<<<BN * 16 * NJP, 256, 0, stream>>>(ccls, pboxes, pposes, labels, prm, img, fg, cost);
    k_sel<<<BN * GN, 256, 0, stream>>>(cost, pboxes, prm, candcv, candci, dkArr, rowmask);
    k_stalepen<<<dim3(QN / 256, BN), 256, 0, stream>>>(rowmask, pen, colcnt, staleCount, staleList);
    k_stalefix<<<256, 256, 0, stream>>>(cost, rowmask, colcnt, staleCount, staleList, fixBj);
    k_assign<<<BN * GN, 256, 0, stream>>>(cost, pen, colcnt, rowmask, assign);
    k_outrows<<<dim3(QN / 256, BN), 256, 0, stream>>>(rowmask, out);
    k_outcols<<<BN, 256, 0, stream>>>(cost, rowmask, assign, candcv, candci, dkArr,
                                      staleCount, staleList, fixBj, out);
}

// Round 9
// 321.013 us; speedup vs baseline: 2.3603x; 1.1941x over previous
//
#include <hip/hip_runtime.h>
#include <cfloat>
#include <climits>
#include <math.h>

#define BN 16
#define QN 4096
#define GN 256
#define CN 80
#define NJP 8              // column strips in k_cost
#define JPB (GN / NJP)     // 32 columns per block
#define PSTR 32            // param stride (floats)

typedef unsigned long long u64;

__device__ __forceinline__ bool lexLessF(float a, int ia, float b, int ib) {
    return (a < b) || (a == b && ia < ib);
}

// ---------------- zero init (rowmask + colcnt + staleCount) ----------------
__global__ void k_zero(u64* __restrict__ p, int n) {
    int i = blockIdx.x * blockDim.x + threadIdx.x;
    if (i < n) p[i] = 0ull;
}

// ---------------- focal class-cost table + per-column param table ----------------
// ccls[b][c][i]; blocks with iblk==0 additionally build prm[b][j][PSTR].
__global__ __launch_bounds__(256) void k_class(const float* __restrict__ logits,
                                               const float* __restrict__ gtb,
                                               const float* __restrict__ gtt,
                                               const float* __restrict__ gtr,
                                               const float* __restrict__ imgt,
                                               float* __restrict__ ccls,
                                               float* __restrict__ prm) {
#pragma clang fp contract(off)
    const int b = blockIdx.x >> 6, iblk = blockIdx.x & 63;
    const int lane = threadIdx.x & 63, cg = threadIdx.x >> 6;  // 4 c-groups x 20
    const int i = iblk * 64 + lane;
    const float* lrow = logits + ((size_t)(b * QN + i)) * CN + cg * 20;
    // 20 classes via 5 float4 loads (16B-aligned: row stride 320B, cg*80B)
#pragma unroll
    for (int q = 0; q < 5; q++) {
        const float4 xv = *reinterpret_cast<const float4*>(lrow + q * 4);
        float xs[4] = {xv.x, xv.y, xv.z, xv.w};
#pragma unroll
        for (int u = 0; u < 4; u++) {
            float x = xs[u];
            float e = (float)exp(-(double)x);
            float pr = 1.0f / (1.0f + e);
            float om = 1.0f - pr;
            float lneg = (float)log((double)(om + 1e-8f));
            float lpos = (float)log((double)(pr + 1e-8f));
            float neg = (0.75f * (pr * pr)) * (-lneg);
            float pos = (0.25f * (om * om)) * (-lpos);
            int c = cg * 20 + q * 4 + u;
            ccls[((size_t)b * CN + c) * QN + i] = pos - neg;
        }
    }
    if (iblk == 0) {
        const int j = threadIdx.x;
        const float* g = gtb + ((size_t)(b * GN + j)) * 4;
        const float g0 = g[0], g1 = g[1], g2 = g[2], g3 = g[3];
        const float* it = imgt + ((size_t)(b * GN + j)) * 4;
        float* P = prm + (size_t)(b * GN + j) * PSTR;
        P[0] = g0; P[1] = g1; P[2] = g2; P[3] = g3;
        P[4] = g0 / it[0]; P[5] = g1 / it[1]; P[6] = g2 / it[2]; P[7] = g3 / it[3];
        P[8] = gtt[(b * GN + j) * 3 + 0]; P[9] = gtt[(b * GN + j) * 3 + 1]; P[10] = gtt[(b * GN + j) * 3 + 2];
        P[11] = gtr[(b * GN + j) * 3 + 0]; P[12] = gtr[(b * GN + j) * 3 + 1]; P[13] = gtr[(b * GN + j) * 3 + 2];
        P[14] = (g2 - g0) * (g3 - g1);   // ga
        // box-test bounds (same op sequence as reference)
        float gcx = (g0 + g2) * 0.5f, gcy = (g1 + g3) * 0.5f;
        float gw = g2 - g0, gh = g3 - g1;
        float X0 = gcx - gw * 0.5f, Y0 = gcy - gh * 0.5f;
        float X1 = gcx + gw * 0.5f, Y1 = gcy + gh * 0.5f;
        float Wd = X1 - X0, Hd = Y1 - Y0;
        P[15] = X0; P[16] = Y0; P[17] = X1; P[18] = Y1;
        P[19] = gcx - 2.5f * Wd; P[20] = gcx + 2.5f * Wd;
        P[21] = gcy - 2.5f * Hd; P[22] = gcy + 2.5f * Hd;
    }
}

// ---------------- fg per query row, 4-way j-split for occupancy ----------------
// Part p tests GT boxes [p*64, p*64+64) and writes byte p of fgp[row]'s u32.
// Union over parts == any over all 256 boxes (exact same f32 tests).
__global__ __launch_bounds__(256) void k_fg(const float* __restrict__ gtb,
                                            const float* __restrict__ pb,
                                            unsigned char* __restrict__ fgp) {
#pragma clang fp contract(off)
    const int b = blockIdx.y;
    const int part = blockIdx.z;
    const int i = blockIdx.x * 256 + threadIdx.x;
    __shared__ float s[64][8];
    if (threadIdx.x < 64) {
        const int j = part * 64 + threadIdx.x;
        const float* g = gtb + ((size_t)(b * GN + j)) * 4;
        float g0 = g[0], g1 = g[1], g2 = g[2], g3 = g[3];
        float gcx = (g0 + g2) * 0.5f, gcy = (g1 + g3) * 0.5f;
        float gw = g2 - g0, gh = g3 - g1;
        float x0 = gcx - gw * 0.5f, y0 = gcy - gh * 0.5f;
        float x1 = gcx + gw * 0.5f, y1 = gcy + gh * 0.5f;
        float w = x1 - x0, h = y1 - y0;
        s[threadIdx.x][0] = x0; s[threadIdx.x][1] = y0; s[threadIdx.x][2] = x1; s[threadIdx.x][3] = y1;
        s[threadIdx.x][4] = gcx - 2.5f * w; s[threadIdx.x][5] = gcx + 2.5f * w;
        s[threadIdx.x][6] = gcy - 2.5f * h; s[threadIdx.x][7] = gcy + 2.5f * h;
    }
    __syncthreads();
    const float4 bb = *reinterpret_cast<const float4*>(pb + ((size_t)(b * QN + i)) * 4);
    float ax = (bb.x + bb.z) * 0.5f, ay = (bb.y + bb.w) * 0.5f;
    bool anyib = false, anyic = false;
#pragma unroll 8
    for (int j = 0; j < 64; j++) {
        bool ib = (ax > s[j][0]) && (ax < s[j][2]) && (ay > s[j][1]) && (ay < s[j][3]);
        bool ic = (ax > s[j][4]) && (ax < s[j][5]) && (ay > s[j][6]) && (ay < s[j][7]);
        anyib |= ib; anyic |= ic;
    }
    fgp[((size_t)b * QN + i) * 4 + part] = (anyib || anyic) ? 1 : 0;
}

// ---------------- cost matrix: pure streaming, NO selection ----------------
// Block = (b, 256-row tile, 32-column strip). Row data in registers once;
// column params via uniform loads from prm. Inner loop: 1 gather + 1 store.
__global__ __launch_bounds__(256) void k_cost(
    const float* __restrict__ ccls, const float* __restrict__ pboxes,
    const float* __restrict__ pposes, const int* __restrict__ labels,
    const float* __restrict__ prm, const float* __restrict__ img,
    const unsigned int* __restrict__ fgw, float* __restrict__ cost) {
#pragma clang fp contract(off)
    const int t = threadIdx.x;
    const int b = blockIdx.x >> 7;
    const int rem = blockIdx.x & 127;
    const int itile = rem >> 3, jp = rem & 7;
    const int i = itile * 256 + t;
    const int j0 = jp * JPB;

    const float im0 = img[b * 4 + 0], im1 = img[b * 4 + 1], im2 = img[b * 4 + 2], im3 = img[b * 4 + 3];
    const float4 bx = *reinterpret_cast<const float4*>(pboxes + ((size_t)(b * QN + i)) * 4);
    const float b0 = bx.x, b1 = bx.y, b2 = bx.z, b3 = bx.w;
    const float2* pp2 = reinterpret_cast<const float2*>(pposes + ((size_t)(b * QN + i)) * 6);
    const float2 q0 = pp2[0], q1 = pp2[1], q2 = pp2[2];
    const float p0 = q0.x, p1 = q0.y, p2 = q1.x, p3 = q1.y, p4 = q2.x, p5 = q2.y;
    const float fgadd = fgw[(size_t)b * QN + i] ? 0.0f : 10000.0f;

    // row-common (bit-identical hoists, verified r6/r7)
    const float bn0 = b0 / im0, bn1 = b1 / im1, bn2 = b2 / im2, bn3 = b3 / im3;
    const float a1 = (b2 - b0) * (b3 - b1);
    const float ax = (b0 + b2) * 0.5f, ay = (b1 + b3) * 0.5f;

    for (int jj = 0; jj < JPB; jj++) {
        const int j = j0 + jj;
        const float* P = prm + (size_t)(b * GN + j) * PSTR;   // uniform -> scalar loads
        const float g0 = P[0], g1 = P[1], g2 = P[2], g3 = P[3];
        const float cc = ccls[((size_t)b * CN + labels[b * GN + j]) * QN + i];

        // iou / giou (f32, reference op order)
        float ga = P[14];
        float ltx = fmaxf(b0, g0), lty = fmaxf(b1, g1);
        float rbx = fminf(b2, g2), rby = fminf(b3, g3);
        float w = fmaxf(rbx - ltx, 0.0f), h = fmaxf(rby - lty, 0.0f);
        float inter = w * h;
        float uni = (a1 + ga) - inter;
        float iou = inter / uni;
        float eltx = fminf(b0, g0), elty = fminf(b1, g1);
        float erbx = fmaxf(b2, g2), erby = fmaxf(b3, g3);
        float ew = fmaxf(erbx - eltx, 0.0f), eh = fmaxf(erby - elty, 0.0f);
        float earea = ew * eh;
        float giou = iou - (earea - uni) / earea;

        // normalized bbox L1 (sequential f32)
        float cb = fabsf(bn0 - P[4]);
        cb = cb + fabsf(bn1 - P[5]);
        cb = cb + fabsf(bn2 - P[6]);
        cb = cb + fabsf(bn3 - P[7]);
        // pose L1
        float ct = fabsf(p0 - P[8]); ct = ct + fabsf(p1 - P[9]); ct = ct + fabsf(p2 - P[10]);
        float cr = fabsf(p3 - P[11]); cr = cr + fabsf(p4 - P[12]); cr = cr + fabsf(p5 - P[13]);
        // both = in_box & in_ctr
        bool ib = (ax > P[15]) && (ax < P[17]) && (ay > P[16]) && (ay < P[18]);
        bool ic = (ax > P[19]) && (ax < P[20]) && (ay > P[21]) && (ay < P[22]);
        bool nb = !(ib && ic);

        float d = 5.0f * cb;
        d = d + 2.0f * cc;
        d = d + 2.0f * (-giou);
        d = d + (nb ? 100.0f : 0.0f);
        d = d + ct;
        d = d + cr;
        d = d + fgadd;

        cost[(size_t)(b * GN + j) * QN + i] = d;
    }
}

// ---------------- per-column selection: bottom-5 cost + top-5 iou + dk ----------------
// Reads cost column (contiguous) + recomputes iou (identical ops). Static cascades.
__global__ __launch_bounds__(256) void k_sel(const float* __restrict__ cost,
                                             const float* __restrict__ pboxes,
                                             const float* __restrict__ prm,
                                             float* __restrict__ candcv, int* __restrict__ candci,
                                             int* __restrict__ dkArr, u64* __restrict__ rowmask) {
#pragma clang fp contract(off)
    const int t = threadIdx.x;
    const int b = blockIdx.x >> 8, j = blockIdx.x & 255;
    const float* P = prm + (size_t)(b * GN + j) * PSTR;
    const float g0 = P[0], g1 = P[1], g2 = P[2], g3 = P[3], ga = P[14];
    const float* cc = cost + (size_t)(b * GN + j) * QN;

    float cv[5]; int ci[5]; float iv[5];
#pragma unroll
    for (int k = 0; k < 5; k++) { cv[k] = FLT_MAX; ci[k] = INT_MAX; iv[k] = -1.0f; }

    for (int kk = 0; kk < QN / 256; kk++) {
        const int i = kk * 256 + t;
        const float d = cc[i];
        const float4 bx = *reinterpret_cast<const float4*>(pboxes + ((size_t)(b * QN + i)) * 4);
        const float b0 = bx.x, b1 = bx.y, b2 = bx.z, b3 = bx.w;
        float a1 = (b2 - b0) * (b3 - b1);
        float ltx = fmaxf(b0, g0), lty = fmaxf(b1, g1);
        float rbx = fminf(b2, g2), rby = fminf(b3, g3);
        float w = fmaxf(rbx - ltx, 0.0f), h = fmaxf(rby - lty, 0.0f);
        float inter = w * h;
        float uni = (a1 + ga) - inter;
        float iou = inter / uni;

        if (lexLessF(d, i, cv[4], ci[4])) {
            float dv = d; int di = i;
#pragma unroll
            for (int k = 0; k < 5; k++) {
                bool sw = lexLessF(dv, di, cv[k], ci[k]);
                float tv = sw ? cv[k] : dv; int ti = sw ? ci[k] : di;
                cv[k] = sw ? dv : cv[k]; ci[k] = sw ? di : ci[k];
                dv = tv; di = ti;
            }
        }
        if (iou > iv[4]) {
            float fv = iou;
#pragma unroll
            for (int k = 0; k < 5; k++) {
                bool sw = fv > iv[k];
                float tv = sw ? iv[k] : fv;
                iv[k] = sw ? fv : iv[k];
                fv = tv;
            }
        }
    }

    __shared__ float scv[256 * 5];
    __shared__ int sci[256 * 5];
    __shared__ float siv[256 * 5];
#pragma unroll
    for (int k = 0; k < 5; k++) { scv[t * 5 + k] = cv[k]; sci[t * 5 + k] = ci[k]; siv[t * 5 + k] = iv[k]; }

    for (int s = 128; s > 0; s >>= 1) {
        __syncthreads();
        if (t < s) {
            float rv[5]; int ri[5]; float fr[5];
#pragma unroll
            for (int k = 0; k < 5; k++) { rv[k] = scv[t * 5 + k]; ri[k] = sci[t * 5 + k]; fr[k] = siv[t * 5 + k]; }
#pragma unroll
            for (int m = 0; m < 5; m++) {
                float dv = scv[(t + s) * 5 + m]; int di = sci[(t + s) * 5 + m];
                if (lexLessF(dv, di, rv[4], ri[4])) {
#pragma unroll
                    for (int k = 0; k < 5; k++) {
                        bool sw = lexLessF(dv, di, rv[k], ri[k]);
                        float tv = sw ? rv[k] : dv; int ti = sw ? ri[k] : di;
                        rv[k] = sw ? dv : rv[k]; ri[k] = sw ? di : ri[k];
                        dv = tv; di = ti;
                    }
                }
                float fv = siv[(t + s) * 5 + m];
                if (fv > fr[4]) {
#pragma unroll
                    for (int k = 0; k < 5; k++) {
                        bool sw = fv > fr[k];
                        float tv = sw ? fr[k] : fv;
                        fr[k] = sw ? fv : fr[k];
                        fv = tv;
                    }
                }
            }
#pragma unroll
            for (int k = 0; k < 5; k++) { scv[t * 5 + k] = rv[k]; sci[t * 5 + k] = ri[k]; siv[t * 5 + k] = fr[k]; }
        }
    }
    __syncthreads();
    if (t == 0) {
        float sum = ((((siv[0] + siv[1]) + siv[2]) + siv[3]) + siv[4]);  // desc order
        int dk = (int)sum;
        if (dk < 1) dk = 1;
        if (dk > 5) dk = 5;
        const int col = b * GN + j;
        dkArr[col] = dk;
#pragma unroll
        for (int k = 0; k < 5; k++) { candcv[(size_t)col * 5 + k] = scv[k]; candci[(size_t)col * 5 + k] = sci[k]; }
        for (int k = 0; k < dk; k++) {
            int i = sci[k];
            atomicOr(&rowmask[((size_t)(b * QN + i)) * 4 + (j >> 6)], 1ull << (j & 63));
        }
    }
}

// ---------------- stale detect + pen + colcnt (non-stale rows) ----------------
__global__ __launch_bounds__(256) void k_stalepen(u64* __restrict__ rowmask,
                                                  unsigned char* __restrict__ pen,
                                                  int* __restrict__ colcnt,
                                                  int* __restrict__ staleCount,
                                                  int* __restrict__ staleList) {
    int b = blockIdx.y;
    int i = blockIdx.x * 256 + threadIdx.x;
    u64* rm = rowmask + ((size_t)(b * QN + i)) * 4;
    u64 w0 = rm[0], w1 = rm[1], w2 = rm[2], w3 = rm[3];
    int cnt = __popcll(w0) + __popcll(w1) + __popcll(w2) + __popcll(w3);
    pen[(size_t)b * QN + i] = (cnt > 0) ? 1 : 0;
    if (cnt > 1) {
        int idx = atomicAdd(staleCount, 1);
        staleList[idx] = (b << 12) | i;
    } else if (cnt == 1) {
        u64 w; int base;
        if (w0) { w = w0; base = 0; }
        else if (w1) { w = w1; base = 64; }
        else if (w2) { w = w2; base = 128; }
        else { w = w3; base = 192; }
        int j = base + (__ffsll((long long)w) - 1);
        atomicAdd(&colcnt[b * GN + j], 1);
    }
}

// ---------------- stale fix: row -> one_hot(argmin_j cost); record bj ----------------
__global__ __launch_bounds__(256) void k_stalefix(const float* __restrict__ cost,
                                                  u64* __restrict__ rowmask,
                                                  int* __restrict__ colcnt,
                                                  const int* __restrict__ staleCount,
                                                  const int* __restrict__ staleList,
                                                  int* __restrict__ fixBj) {
    int gtid = blockIdx.x * blockDim.x + threadIdx.x;
    int wid = gtid >> 6;
    int lane = threadIdx.x & 63;
    int nw = (gridDim.x * blockDim.x) >> 6;
    int n = *staleCount;
    for (int e = wid; e < n; e += nw) {
        int pk = staleList[e];
        int b = pk >> 12, i = pk & 4095;
        const float* cb = cost + (size_t)b * GN * QN + i;
        float best = FLT_MAX; int bj = GN;
        for (int k = 0; k < GN; k += 64) {
            int j = k + lane;
            float v = cb[(size_t)j * QN];
            if (lexLessF(v, j, best, bj)) { best = v; bj = j; }
        }
        for (int off = 32; off > 0; off >>= 1) {
            float ov = __shfl_down(best, off, 64);
            int oj = __shfl_down(bj, off, 64);
            if (lexLessF(ov, oj, best, bj)) { best = ov; bj = oj; }
        }
        if (lane == 0) {
            u64* rm = rowmask + ((size_t)(b * QN + i)) * 4;
            rm[0] = ((bj >> 6) == 0) ? (1ull << (bj & 63)) : 0ull;
            rm[1] = ((bj >> 6) == 1) ? (1ull << (bj & 63)) : 0ull;
            rm[2] = ((bj >> 6) == 2) ? (1ull << (bj & 63)) : 0ull;
            rm[3] = ((bj >> 6) == 3) ? (1ull << (bj & 63)) : 0ull;
            atomicAdd(&colcnt[b * GN + bj], 1);
            fixBj[e] = bj;
        }
    }
}

// ---------------- assign unmatched columns to cheapest unmatched row ----------------
__global__ __launch_bounds__(256) void k_assign(const float* __restrict__ cost,
                                                const unsigned char* __restrict__ pen,
                                                const int* __restrict__ colcnt,
                                                u64* __restrict__ rowmask,
                                                int* __restrict__ assign) {
    int b = blockIdx.x >> 8, j = blockIdx.x & 255;
    if (colcnt[b * GN + j] != 0) {
        if (threadIdx.x == 0) assign[b * GN + j] = -1;
        return;
    }
    const float* cc = cost + ((size_t)(b * GN + j)) * QN;
    const unsigned char* pp = pen + (size_t)b * QN;
    float best = FLT_MAX; int bi = INT_MAX;
    for (int k = threadIdx.x; k < QN; k += 256) {
        if (!pp[k]) {
            float v = cc[k];
            if (lexLessF(v, k, best, bi)) { best = v; bi = k; }
        }
    }
    __shared__ float sv[256];
    __shared__ int si[256];
    sv[threadIdx.x] = best; si[threadIdx.x] = bi;
    for (int s = 128; s > 0; s >>= 1) {
        __syncthreads();
        if (threadIdx.x < s) {
            float ov = sv[threadIdx.x + s]; int oi = si[threadIdx.x + s];
            if (lexLessF(ov, oi, sv[threadIdx.x], si[threadIdx.x])) {
                sv[threadIdx.x] = ov; si[threadIdx.x] = oi;
            }
        }
    }
    if (threadIdx.x == 0) {
        int r = si[0];
        assign[b * GN + j] = r;
        atomicOr(&rowmask[((size_t)(b * QN + r)) * 4 + (j >> 6)], 1ull << (j & 63));
    }
}

// ---------------- per-row outputs: selected, gt_idx ----------------
__global__ __launch_bounds__(256) void k_outrows(const u64* __restrict__ rowmask,
                                                 int* __restrict__ out) {
    int b = blockIdx.y;
    int i = blockIdx.x * 256 + threadIdx.x;
    const u64* rm = rowmask + ((size_t)(b * QN + i)) * 4;
    u64 w0 = rm[0], w1 = rm[1], w2 = rm[2], w3 = rm[3];
    int sel = (w0 | w1 | w2 | w3) ? 1 : 0;
    int g = 0;
    if (w0) g = __ffsll((long long)w0) - 1;
    else if (w1) g = 64 + __ffsll((long long)w1) - 1;
    else if (w2) g = 128 + __ffsll((long long)w2) - 1;
    else if (w3) g = 192 + __ffsll((long long)w3) - 1;
    out[(size_t)b * QN + i] = sel;
    out[(size_t)BN * QN + (size_t)b * QN + i] = g;
}

// ---------------- per-column output: matched_qidx (candidate-based) ----------------
__global__ __launch_bounds__(256) void k_outcols(const float* __restrict__ cost,
                                                 const u64* __restrict__ rowmask,
                                                 const int* __restrict__ assign,
                                                 const float* __restrict__ candcv,
                                                 const int* __restrict__ candci,
                                                 const int* __restrict__ dkArr,
                                                 const int* __restrict__ staleCount,
                                                 const int* __restrict__ staleList,
                                                 const int* __restrict__ fixBj,
                                                 int* __restrict__ out) {
    const int b = blockIdx.x;
    const int j = threadIdx.x;
    const int col = b * GN + j;
    int* o = out + (size_t)2 * BN * QN + col;
    int a = assign[col];
    if (a >= 0) { *o = a; return; }
    const u64 bit = 1ull << (j & 63);
    const int w = j >> 6;
    float best = FLT_MAX; int bi = INT_MAX;
    const int dk = dkArr[col];
    for (int k = 0; k < 5; k++) {
        if (k < dk) {
            int i = candci[(size_t)col * 5 + k];
            if (rowmask[((size_t)(b * QN + i)) * 4 + w] & bit) {
                float pv = candcv[(size_t)col * 5 + k] + 100000.0f;
                if (lexLessF(pv, i, best, bi)) { best = pv; bi = i; }
            }
        }
    }
    const int n = *staleCount;
    for (int e = 0; e < n; e++) {
        int pk = staleList[e];
        int eb = pk >> 12, ei = pk & 4095;
        if (eb == b && fixBj[e] == j) {
            float pv = cost[(size_t)col * QN + ei] + 100000.0f;
            if (lexLessF(pv, ei, best, bi)) { best = pv; bi = ei; }
        }
    }
    *o = (bi == INT_MAX) ? 0 : bi;
}

extern "C" void kernel_launch(void* const* d_in, const int* in_sizes, int n_in,
                              void* d_out, int out_size, void* d_ws, size_t ws_size,
                              hipStream_t stream) {
    const float* logits = (const float*)d_in[0];
    const float* pboxes = (const float*)d_in[1];
    const float* pposes = (const float*)d_in[2];
    const int* labels = (const int*)d_in[3];
    const float* gtb = (const float*)d_in[4];
    const float* gtt = (const float*)d_in[5];
    const float* gtr = (const float*)d_in[6];
    const float* img = (const float*)d_in[7];
    const float* imgt = (const float*)d_in[8];
    int* out = (int*)d_out;

    char* p = (char*)d_ws;
    float* cost = (float*)p;             p += (size_t)BN * GN * QN * 4;      // 64 MiB
    float* ccls = (float*)p;             p += (size_t)BN * CN * QN * 4;      // 20 MiB
    u64* rowmask = (u64*)p;              size_t rb = (size_t)BN * QN * 4 * 8; p += rb;  // 2 MiB
    int* colcnt = (int*)p;               p += (size_t)BN * GN * 4;            // 16 KiB
    int* staleCount = (int*)p;           p += 64;
    int* staleList = (int*)p;            p += (size_t)BN * QN * 4;            // 256 KiB
    int* fixBj = (int*)p;                p += (size_t)BN * QN * 4;            // 256 KiB
    unsigned char* pen = (unsigned char*)p; p += (size_t)BN * QN;             // 64 KiB
    unsigned char* fgp = (unsigned char*)p; p += (size_t)BN * QN * 4;         // 256 KiB
    int* assign = (int*)p;               p += (size_t)BN * GN * 4;            // 16 KiB
    float* prm = (float*)p;              p += (size_t)BN * GN * PSTR * 4;     // 512 KiB
    float* candcv = (float*)p;           p += (size_t)BN * GN * 5 * 4;        // 80 KiB
    int* candci = (int*)p;               p += (size_t)BN * GN * 5 * 4;        // 80 KiB
    int* dkArr = (int*)p;                p += (size_t)BN * GN * 4;            // 16 KiB

    // zero rowmask + colcnt + staleCount (contiguous)
    int zn = (int)((rb + (size_t)BN * GN * 4 + 64) / 8);
    k_zero<<<(zn + 255) / 256, 256, 0, stream>>>(rowmask, zn);

    k_class<<<BN * 64, 256, 0, stream>>>(logits, gtb, gtt, gtr, imgt, ccls, prm);
    k_fg<<<dim3(QN / 256, BN, 4), 256, 0, stream>>>(gtb, pboxes, fgp);
    k_cost<<<BN * 16 * NJP, 256, 0, stream>>>(ccls, pboxes, pposes, labels, prm, img,
                                              (const unsigned int*)fgp, cost);
    k_sel<<<BN * GN, 256, 0, stream>>>(cost, pboxes, prm, candcv, candci, dkArr, rowmask);
    k_stalepen<<<dim3(QN / 256, BN), 256, 0, stream>>>(rowmask, pen, colcnt, staleCount, staleList);
    k_stalefix<<<256, 256, 0, stream>>>(cost, rowmask, colcnt, staleCount, staleList, fixBj);
    k_assign<<<BN * GN, 256, 0, stream>>>(cost, pen, colcnt, rowmask, assign);
    k_outrows<<<dim3(QN / 256, BN), 256, 0, stream>>>(rowmask, out);
    k_outcols<<<BN, 256, 0, stream>>>(cost, rowmask, assign, candcv, candci, dkArr,
                                      staleCount, staleList, fixBj, out);
}